// Round 9
// baseline (149.351 us; speedup 1.0000x reference)
//
#include <hip/hip_runtime.h>

typedef float f32x4 __attribute__((ext_vector_type(4)));

#define D_IN 1024

// tanh(x) = 1 - 2/(exp(2x)+1): v_exp + v_rcp, robust for all x
__device__ __forceinline__ float fast_tanh(float x) {
  float e = __expf(2.0f * x);
  return 1.0f - 2.0f * __builtin_amdgcn_rcpf(e + 1.0f);
}

// ---------------------------------------------------------------------------
// Fused kernel, 2 rows per wave in flight (independent chains interleave ->
// half the effective serial latency per row, 2x HBM bytes in flight).
// W1 in LDS; prologue per block: stage W1, evolve V, form M_i in LDS.
// ---------------------------------------------------------------------------
__global__ __launch_bounds__(256, 4) void fused_qenc_kernel(
    const float* __restrict__ x, const float* __restrict__ W1,
    const float* __restrict__ b1, const float* __restrict__ theta,
    const float* __restrict__ Wmu, const float* __restrict__ bmu,
    const float* __restrict__ Wlv, const float* __restrict__ blv,
    float* __restrict__ out, int B) {
  __shared__ float Vre[16][17];
  __shared__ float Vim[16][17];
  __shared__ float Mlds[4][16][16];
  __shared__ f32x4 W1L[1024];  // j*256 + k*64 + lane

  const int tid = threadIdx.x;

  // ---- prologue: stage W1 rows 0..3 into LDS ----
  {
    const f32x4* wp = reinterpret_cast<const f32x4*>(W1);
#pragma unroll
    for (int k = 0; k < 4; ++k) W1L[k * 256 + tid] = wp[k * 256 + tid];
  }

  // ---- prologue: evolve V on threads 0..15 ----
  if (tid < 16) {
    float re[16], im[16];
#pragma unroll
    for (int z = 0; z < 16; ++z) { re[z] = 0.f; im[z] = 0.f; }
    re[tid] = 1.f;
    for (int layer = 0; layer < 2; ++layer) {
#pragma unroll
      for (int q = 0; q < 4; ++q) {
        float th = theta[layer * 4 + q];
        float s, c;
        __sincosf(0.5f * th, &s, &c);
        // Rx
#pragma unroll
        for (int z = 0; z < 16; ++z) {
          if (!((z >> q) & 1)) {
            int z1 = z | (1 << q);
            float ar = re[z], ai = im[z], br = re[z1], bi = im[z1];
            re[z]  = c * ar + s * bi;  im[z]  = c * ai - s * br;
            re[z1] = c * br + s * ai;  im[z1] = c * bi - s * ar;
          }
        }
        // Ry
#pragma unroll
        for (int z = 0; z < 16; ++z) {
          if (!((z >> q) & 1)) {
            int z1 = z | (1 << q);
            float ar = re[z], ai = im[z], br = re[z1], bi = im[z1];
            re[z]  = c * ar - s * br;  im[z]  = c * ai - s * bi;
            re[z1] = s * ar + c * br;  im[z1] = s * ai + c * bi;
          }
        }
        // Rz
#pragma unroll
        for (int z = 0; z < 16; ++z) {
          if (!((z >> q) & 1)) {
            int z1 = z | (1 << q);
            float ar = re[z], ai = im[z], br = re[z1], bi = im[z1];
            re[z]  = c * ar + s * ai;  im[z]  = c * ai - s * ar;
            re[z1] = c * br - s * bi;  im[z1] = c * bi + s * br;
          }
        }
      }
      // CNOT ring (0,1)(1,2)(2,3)(3,0)
      const int cqs[4] = {0, 1, 2, 3};
      const int tqs[4] = {1, 2, 3, 0};
#pragma unroll
      for (int gIdx = 0; gIdx < 4; ++gIdx) {
#pragma unroll
        for (int z = 0; z < 16; ++z) {
          if (((z >> cqs[gIdx]) & 1) && !((z >> tqs[gIdx]) & 1)) {
            int z1 = z | (1 << tqs[gIdx]);
            float tr = re[z], ti = im[z];
            re[z] = re[z1];  im[z] = im[z1];
            re[z1] = tr;     im[z1] = ti;
          }
        }
      }
    }
#pragma unroll
    for (int z = 0; z < 16; ++z) { Vre[z][tid] = re[z]; Vim[z][tid] = im[z]; }
  }
  __syncthreads();

  // ---- prologue: M formation ----
  {
    const int i = tid >> 6, a = (tid >> 2) & 15, b0 = (tid & 3) * 4;
    float ra[16], ia[16];
#pragma unroll
    for (int z = 0; z < 16; ++z) { ra[z] = Vre[z][a]; ia[z] = Vim[z][a]; }
#pragma unroll
    for (int k = 0; k < 4; ++k) {
      const int b = b0 + k;
      float acc = 0.f;
#pragma unroll
      for (int z = 0; z < 16; ++z) {
        float sg = ((z >> (3 - i)) & 1) ? -1.f : 1.f;
        acc += sg * (ra[z] * Vre[z][b] + ia[z] * Vim[z][b]);
      }
      Mlds[i][a][b] = acc;
    }
  }
  __syncthreads();

  // ---- main-loop invariants ----
  const int lane = tid & 63;
  const int wave = blockIdx.x * 4 + (tid >> 6);
  const int nwaves = gridDim.x * 4;
  const int g = lane >> 4;
  const int mz = lane & 15;
  const bool bit4 = (lane & 16) != 0;
  const bool bit5 = (lane & 32) != 0;

  float Mr[16];
#pragma unroll
  for (int k = 0; k < 16; ++k) Mr[k] = Mlds[g][mz][k];

  float b1r[4];
#pragma unroll
  for (int j = 0; j < 4; ++j) b1r[j] = b1[j];

  float wmuP[4], wlvP[4];
#pragma unroll
  for (int k = 0; k < 4; ++k) {
    wmuP[k] = Wmu[lane * 4 + (g ^ k)];
    wlvP[k] = Wlv[lane * 4 + (g ^ k)];
  }
  const float bmur = bmu[lane], blvr = blv[lane];
  const size_t lv_base = (size_t)B * 64;

  // two rows in flight: rA = wave, rB = wave + nwaves
  int rA = wave;
  int rB = wave + nwaves;
  if (rA >= B) return;

  f32x4 xv[4], yv[4];
  {
    const f32x4* xp = reinterpret_cast<const f32x4*>(x + (size_t)rA * D_IN);
#pragma unroll
    for (int k = 0; k < 4; ++k) xv[k] = __builtin_nontemporal_load(xp + k * 64 + lane);
  }
  bool haveB = (rB < B);
  if (haveB) {
    const f32x4* yp = reinterpret_cast<const f32x4*>(x + (size_t)rB * D_IN);
#pragma unroll
    for (int k = 0; k < 4; ++k) yv[k] = __builtin_nontemporal_load(yp + k * 64 + lane);
  }

  while (true) {
    // ---- dot partials for both rows (independent chains) ----
    float acc[4] = {0.f, 0.f, 0.f, 0.f};
    float bcc[4] = {0.f, 0.f, 0.f, 0.f};
#pragma unroll
    for (int k = 0; k < 4; ++k) {
      f32x4 xk = xv[k];
      f32x4 yk = yv[k];
#pragma unroll
      for (int j = 0; j < 4; ++j) {
        f32x4 w = W1L[j * 256 + k * 64 + lane];
        acc[j] = fmaf(xk.x, w.x, acc[j]);
        acc[j] = fmaf(xk.y, w.y, acc[j]);
        acc[j] = fmaf(xk.z, w.z, acc[j]);
        acc[j] = fmaf(xk.w, w.w, acc[j]);
        bcc[j] = fmaf(yk.x, w.x, bcc[j]);
        bcc[j] = fmaf(yk.y, w.y, bcc[j]);
        bcc[j] = fmaf(yk.z, w.z, bcc[j]);
        bcc[j] = fmaf(yk.w, w.w, bcc[j]);
      }
    }

    // ---- prefetch next pair ----
    const int rA2 = rA + 2 * nwaves;
    const int rB2 = rB + 2 * nwaves;
    if (rA2 < B) {
      const f32x4* xp = reinterpret_cast<const f32x4*>(x + (size_t)rA2 * D_IN);
#pragma unroll
      for (int k = 0; k < 4; ++k) xv[k] = __builtin_nontemporal_load(xp + k * 64 + lane);
    }
    if (rB2 < B) {
      const f32x4* yp = reinterpret_cast<const f32x4*>(x + (size_t)rB2 * D_IN);
#pragma unroll
      for (int k = 0; k < 4; ++k) yv[k] = __builtin_nontemporal_load(yp + k * 64 + lane);
    }

    // ---- fused butterflies, both rows interleaved ----
    float u = bit5 ? acc[1] : acc[0];
    float u2 = bit5 ? bcc[1] : bcc[0];
    u += __shfl_xor(bit5 ? acc[0] : acc[1], 32);
    u2 += __shfl_xor(bit5 ? bcc[0] : bcc[1], 32);
    float v = bit5 ? acc[3] : acc[2];
    float v2 = bit5 ? bcc[3] : bcc[2];
    v += __shfl_xor(bit5 ? acc[2] : acc[3], 32);
    v2 += __shfl_xor(bit5 ? bcc[2] : bcc[3], 32);
    float w = bit4 ? v : u;
    float w2 = bit4 ? v2 : u2;
    w += __shfl_xor(bit4 ? u : v, 16);
    w2 += __shfl_xor(bit4 ? u2 : v2, 16);
#pragma unroll
    for (int off = 8; off; off >>= 1) {
      w += __shfl_xor(w, off);
      w2 += __shfl_xor(w2, off);
    }
    float vA = __shfl_xor(w, 16), vA2 = __shfl_xor(w2, 16);
    float vB = __shfl_xor(w, 32), vB2 = __shfl_xor(w2, 32);
    float vC = __shfl_xor(w, 48), vC2 = __shfl_xor(w2, 48);
    float d0 = bit4 ? (bit5 ? vC : vA) : (bit5 ? vB : w);
    float d1 = bit4 ? (bit5 ? vA : vC) : (bit5 ? w : vB);
    float d2 = bit4 ? (bit5 ? vB : w) : (bit5 ? vC : vA);
    float d3 = bit4 ? (bit5 ? w : vB) : (bit5 ? vA : vC);
    float e0 = bit4 ? (bit5 ? vC2 : vA2) : (bit5 ? vB2 : w2);
    float e1 = bit4 ? (bit5 ? vA2 : vC2) : (bit5 ? w2 : vB2);
    float e2 = bit4 ? (bit5 ? vB2 : w2) : (bit5 ? vC2 : vA2);
    float e3 = bit4 ? (bit5 ? w2 : vB2) : (bit5 ? vA2 : vC2);

    // ---- tails for both rows ----
    float cq[4], sq[4], cr[4], sr[4];
    __sincosf(0.5f * fast_tanh(d0 + b1r[0]), &sq[0], &cq[0]);
    __sincosf(0.5f * fast_tanh(e0 + b1r[0]), &sr[0], &cr[0]);
    __sincosf(0.5f * fast_tanh(d1 + b1r[1]), &sq[1], &cq[1]);
    __sincosf(0.5f * fast_tanh(e1 + b1r[1]), &sr[1], &cr[1]);
    __sincosf(0.5f * fast_tanh(d2 + b1r[2]), &sq[2], &cq[2]);
    __sincosf(0.5f * fast_tanh(e2 + b1r[2]), &sr[2], &cr[2]);
    __sincosf(0.5f * fast_tanh(d3 + b1r[3]), &sq[3], &cq[3]);
    __sincosf(0.5f * fast_tanh(e3 + b1r[3]), &sr[3], &cr[3]);

    const float A0 = cq[0] * cq[1], A1 = sq[0] * cq[1];
    const float A2 = cq[0] * sq[1], A3 = sq[0] * sq[1];
    const float B0 = cq[2] * cq[3], B1 = sq[2] * cq[3];
    const float B2 = cq[2] * sq[3], B3 = sq[2] * sq[3];
    const float C0 = cr[0] * cr[1], C1 = sr[0] * cr[1];
    const float C2 = cr[0] * sr[1], C3 = sr[0] * sr[1];
    const float D0 = cr[2] * cr[3], D1 = sr[2] * cr[3];
    const float D2 = cr[2] * sr[3], D3 = sr[2] * sr[3];

    float t0 = fmaf(Mr[3], A3, fmaf(Mr[2], A2, fmaf(Mr[1], A1, Mr[0] * A0)));
    float t1 = fmaf(Mr[7], A3, fmaf(Mr[6], A2, fmaf(Mr[5], A1, Mr[4] * A0)));
    float t2 = fmaf(Mr[11], A3, fmaf(Mr[10], A2, fmaf(Mr[9], A1, Mr[8] * A0)));
    float t3 = fmaf(Mr[15], A3, fmaf(Mr[14], A2, fmaf(Mr[13], A1, Mr[12] * A0)));
    float tdot = fmaf(t3, B3, fmaf(t2, B2, fmaf(t1, B1, t0 * B0)));
    float s0 = fmaf(Mr[3], C3, fmaf(Mr[2], C2, fmaf(Mr[1], C1, Mr[0] * C0)));
    float s1 = fmaf(Mr[7], C3, fmaf(Mr[6], C2, fmaf(Mr[5], C1, Mr[4] * C0)));
    float s2 = fmaf(Mr[11], C3, fmaf(Mr[10], C2, fmaf(Mr[9], C1, Mr[8] * C0)));
    float s3 = fmaf(Mr[15], C3, fmaf(Mr[14], C2, fmaf(Mr[13], C1, Mr[12] * C0)));
    float sdot = fmaf(s3, D3, fmaf(s2, D2, fmaf(s1, D1, s0 * D0)));

    float svm = ((mz & 1) ? sq[0] : cq[0]);
    svm *= ((mz & 2) ? sq[1] : cq[1]);
    svm *= ((mz & 4) ? sq[2] : cq[2]);
    svm *= ((mz & 8) ? sq[3] : cq[3]);
    float svn = ((mz & 1) ? sr[0] : cr[0]);
    svn *= ((mz & 2) ? sr[1] : cr[1]);
    svn *= ((mz & 4) ? sr[2] : cr[2]);
    svn *= ((mz & 8) ? sr[3] : cr[3]);

    float p = tdot * svm;
    float p2 = sdot * svn;
#pragma unroll
    for (int off = 8; off; off >>= 1) {
      p += __shfl_xor(p, off);
      p2 += __shfl_xor(p2, off);
    }
    float q1 = __shfl_xor(p, 16), q1b = __shfl_xor(p2, 16);
    float q2 = __shfl_xor(p, 32), q2b = __shfl_xor(p2, 32);
    float q3 = __shfl_xor(q1, 32), q3b = __shfl_xor(q1b, 32);

    float mu = fmaf(q3, wmuP[3], fmaf(q2, wmuP[2], fmaf(q1, wmuP[1], fmaf(p, wmuP[0], bmur))));
    float lv = fmaf(q3, wlvP[3], fmaf(q2, wlvP[2], fmaf(q1, wlvP[1], fmaf(p, wlvP[0], blvr))));
    __builtin_nontemporal_store(mu, out + (size_t)rA * 64 + lane);
    __builtin_nontemporal_store(lv, out + lv_base + (size_t)rA * 64 + lane);
    if (haveB) {
      float mu2 = fmaf(q3b, wmuP[3], fmaf(q2b, wmuP[2], fmaf(q1b, wmuP[1], fmaf(p2, wmuP[0], bmur))));
      float lv2 = fmaf(q3b, wlvP[3], fmaf(q2b, wlvP[2], fmaf(q1b, wlvP[1], fmaf(p2, wlvP[0], blvr))));
      __builtin_nontemporal_store(mu2, out + (size_t)rB * 64 + lane);
      __builtin_nontemporal_store(lv2, out + lv_base + (size_t)rB * 64 + lane);
    }

    if (rA2 >= B) break;
    rA = rA2;
    rB = rB2;
    haveB = (rB < B);
  }
}

extern "C" void kernel_launch(void* const* d_in, const int* in_sizes, int n_in,
                              void* d_out, int out_size, void* d_ws, size_t ws_size,
                              hipStream_t stream) {
  const float* x   = (const float*)d_in[0];
  const float* W1  = (const float*)d_in[1];
  const float* b1  = (const float*)d_in[2];
  const float* qp  = (const float*)d_in[3];
  const float* Wmu = (const float*)d_in[4];
  const float* bmu = (const float*)d_in[5];
  const float* Wlv = (const float*)d_in[6];
  const float* blv = (const float*)d_in[7];
  float* out = (float*)d_out;

  const int B = out_size / 128;  // out = mu(B,64) ++ logvar(B,64)

  int blocks = (B + 63) / 64;    // 4 waves/block, 2 rows/wave in flight
  if (blocks > 1024) blocks = 1024;
  fused_qenc_kernel<<<blocks, 256, 0, stream>>>(x, W1, b1, qp, Wmu, bmu, Wlv, blv,
                                                out, B);
}

// Round 10
// 80.775 us; speedup vs baseline: 1.8490x; 1.8490x over previous
//
#include <hip/hip_runtime.h>

typedef float f32x4 __attribute__((ext_vector_type(4)));

#define D_IN 1024

// tanh(x) = 1 - 2/(exp(2x)+1): v_exp + v_rcp, robust for all x
__device__ __forceinline__ float fast_tanh(float x) {
  float e = __expf(2.0f * x);
  return 1.0f - 2.0f * __builtin_amdgcn_rcpf(e + 1.0f);
}

// ---------------------------------------------------------------------------
// DIAGNOSTIC ROUND: round-6 body (validated 44 us, 1 row/wave, W1 in LDS)
// wrapped in a REP=2 repeat inside one dispatch. Outputs are written twice
// (idempotent, deterministic). Purpose: (a) dispatch > 74 us so it appears
// in the rocprof top-5 over the harness fill kernels; (b) marginal cost of
// pass 2 separates fixed per-replay overhead from real GPU work.
// ---------------------------------------------------------------------------
__global__ __launch_bounds__(256, 4) void fused_qenc_kernel(
    const float* __restrict__ x, const float* __restrict__ W1,
    const float* __restrict__ b1, const float* __restrict__ theta,
    const float* __restrict__ Wmu, const float* __restrict__ bmu,
    const float* __restrict__ Wlv, const float* __restrict__ blv,
    float* __restrict__ out, int B) {
  __shared__ float Vre[16][17];
  __shared__ float Vim[16][17];
  __shared__ float Mlds[4][16][16];
  __shared__ f32x4 W1L[1024];  // j*256 + k*64 + lane

  const int tid = threadIdx.x;

  // ---- prologue: stage W1 rows 0..3 into LDS ----
  {
    const f32x4* wp = reinterpret_cast<const f32x4*>(W1);
#pragma unroll
    for (int k = 0; k < 4; ++k) W1L[k * 256 + tid] = wp[k * 256 + tid];
  }

  // ---- prologue: evolve V on threads 0..15 ----
  if (tid < 16) {
    float re[16], im[16];
#pragma unroll
    for (int z = 0; z < 16; ++z) { re[z] = 0.f; im[z] = 0.f; }
    re[tid] = 1.f;
    for (int layer = 0; layer < 2; ++layer) {
#pragma unroll
      for (int q = 0; q < 4; ++q) {
        float th = theta[layer * 4 + q];
        float s, c;
        __sincosf(0.5f * th, &s, &c);
        // Rx
#pragma unroll
        for (int z = 0; z < 16; ++z) {
          if (!((z >> q) & 1)) {
            int z1 = z | (1 << q);
            float ar = re[z], ai = im[z], br = re[z1], bi = im[z1];
            re[z]  = c * ar + s * bi;  im[z]  = c * ai - s * br;
            re[z1] = c * br + s * ai;  im[z1] = c * bi - s * ar;
          }
        }
        // Ry
#pragma unroll
        for (int z = 0; z < 16; ++z) {
          if (!((z >> q) & 1)) {
            int z1 = z | (1 << q);
            float ar = re[z], ai = im[z], br = re[z1], bi = im[z1];
            re[z]  = c * ar - s * br;  im[z]  = c * ai - s * bi;
            re[z1] = s * ar + c * br;  im[z1] = s * ai + c * bi;
          }
        }
        // Rz
#pragma unroll
        for (int z = 0; z < 16; ++z) {
          if (!((z >> q) & 1)) {
            int z1 = z | (1 << q);
            float ar = re[z], ai = im[z], br = re[z1], bi = im[z1];
            re[z]  = c * ar + s * ai;  im[z]  = c * ai - s * ar;
            re[z1] = c * br - s * bi;  im[z1] = c * bi + s * br;
          }
        }
      }
      // CNOT ring (0,1)(1,2)(2,3)(3,0)
      const int cqs[4] = {0, 1, 2, 3};
      const int tqs[4] = {1, 2, 3, 0};
#pragma unroll
      for (int gIdx = 0; gIdx < 4; ++gIdx) {
#pragma unroll
        for (int z = 0; z < 16; ++z) {
          if (((z >> cqs[gIdx]) & 1) && !((z >> tqs[gIdx]) & 1)) {
            int z1 = z | (1 << tqs[gIdx]);
            float tr = re[z], ti = im[z];
            re[z] = re[z1];  im[z] = im[z1];
            re[z1] = tr;     im[z1] = ti;
          }
        }
      }
    }
#pragma unroll
    for (int z = 0; z < 16; ++z) { Vre[z][tid] = re[z]; Vim[z][tid] = im[z]; }
  }
  __syncthreads();

  // ---- prologue: M formation ----
  {
    const int i = tid >> 6, a = (tid >> 2) & 15, b0 = (tid & 3) * 4;
    float ra[16], ia[16];
#pragma unroll
    for (int z = 0; z < 16; ++z) { ra[z] = Vre[z][a]; ia[z] = Vim[z][a]; }
#pragma unroll
    for (int k = 0; k < 4; ++k) {
      const int b = b0 + k;
      float acc = 0.f;
#pragma unroll
      for (int z = 0; z < 16; ++z) {
        float sg = ((z >> (3 - i)) & 1) ? -1.f : 1.f;
        acc += sg * (ra[z] * Vre[z][b] + ia[z] * Vim[z][b]);
      }
      Mlds[i][a][b] = acc;
    }
  }
  __syncthreads();

  // ---- main-loop invariants ----
  const int lane = tid & 63;
  const int wave = blockIdx.x * 4 + (tid >> 6);
  const int nwaves = gridDim.x * 4;
  const int g = lane >> 4;
  const int mz = lane & 15;
  const bool bit4 = (lane & 16) != 0;
  const bool bit5 = (lane & 32) != 0;

  float Mr[16];
#pragma unroll
  for (int k = 0; k < 16; ++k) Mr[k] = Mlds[g][mz][k];

  float b1r[4];
#pragma unroll
  for (int j = 0; j < 4; ++j) b1r[j] = b1[j];

  float wmuP[4], wlvP[4];
#pragma unroll
  for (int k = 0; k < 4; ++k) {
    wmuP[k] = Wmu[lane * 4 + (g ^ k)];
    wlvP[k] = Wlv[lane * 4 + (g ^ k)];
  }
  const float bmur = bmu[lane], blvr = blv[lane];
  const size_t lv_base = (size_t)B * 64;

  for (int rep = 0; rep < 2; ++rep) {
    int r = wave;
    if (r >= B) continue;

    f32x4 xv[4];
    {
      const f32x4* xp = reinterpret_cast<const f32x4*>(x + (size_t)r * D_IN);
#pragma unroll
      for (int k = 0; k < 4; ++k) xv[k] = __builtin_nontemporal_load(xp + k * 64 + lane);
    }

    while (true) {
      // ---- dot partials: W1 frags from LDS, x from regs (last use of xv) ----
      float acc[4] = {0.f, 0.f, 0.f, 0.f};
#pragma unroll
      for (int k = 0; k < 4; ++k) {
        f32x4 xk = xv[k];
#pragma unroll
        for (int j = 0; j < 4; ++j) {
          f32x4 w = W1L[j * 256 + k * 64 + lane];
          acc[j] = fmaf(xk.x, w.x, acc[j]);
          acc[j] = fmaf(xk.y, w.y, acc[j]);
          acc[j] = fmaf(xk.z, w.z, acc[j]);
          acc[j] = fmaf(xk.w, w.w, acc[j]);
        }
      }

      // ---- prefetch next row into the same regs ----
      const int rn = r + nwaves;
      if (rn < B) {
        const f32x4* xp = reinterpret_cast<const f32x4*>(x + (size_t)rn * D_IN);
#pragma unroll
        for (int k = 0; k < 4; ++k) xv[k] = __builtin_nontemporal_load(xp + k * 64 + lane);
      }

      // ---- fused butterfly: 7 shfls reduce all 4 dots ----
      float u = bit5 ? acc[1] : acc[0];
      u += __shfl_xor(bit5 ? acc[0] : acc[1], 32);
      float v = bit5 ? acc[3] : acc[2];
      v += __shfl_xor(bit5 ? acc[2] : acc[3], 32);
      float w = bit4 ? v : u;
      w += __shfl_xor(bit4 ? u : v, 16);
#pragma unroll
      for (int off = 8; off; off >>= 1) w += __shfl_xor(w, off);
      // redistribute: every lane needs all four dots
      float vA = __shfl_xor(w, 16);  // dot_{f^2}
      float vB = __shfl_xor(w, 32);  // dot_{f^1}
      float vC = __shfl_xor(w, 48);  // dot_{f^3}
      float d0 = bit4 ? (bit5 ? vC : vA) : (bit5 ? vB : w);
      float d1 = bit4 ? (bit5 ? vA : vC) : (bit5 ? w : vB);
      float d2 = bit4 ? (bit5 ? vB : w) : (bit5 ? vC : vA);
      float d3 = bit4 ? (bit5 ? w : vB) : (bit5 ? vA : vC);

      // ---- angles -> half-angle (cos, sin) ----
      float cq[4], sq[4];
      __sincosf(0.5f * fast_tanh(d0 + b1r[0]), &sq[0], &cq[0]);
      __sincosf(0.5f * fast_tanh(d1 + b1r[1]), &sq[1], &cq[1]);
      __sincosf(0.5f * fast_tanh(d2 + b1r[2]), &sq[2], &cq[2]);
      __sincosf(0.5f * fast_tanh(d3 + b1r[3]), &sq[3], &cq[3]);

      // rank-1 factors of the product state: sv[z] = A[z&3] * Bf[z>>2]
      const float A0 = cq[0] * cq[1], A1 = sq[0] * cq[1];
      const float A2 = cq[0] * sq[1], A3 = sq[0] * sq[1];
      const float B0 = cq[2] * cq[3], B1 = sq[2] * cq[3];
      const float B2 = cq[2] * sq[3], B3 = sq[2] * sq[3];

      // tdot = M_g[mz][:] . sv
      float t0 = fmaf(Mr[3], A3, fmaf(Mr[2], A2, fmaf(Mr[1], A1, Mr[0] * A0)));
      float t1 = fmaf(Mr[7], A3, fmaf(Mr[6], A2, fmaf(Mr[5], A1, Mr[4] * A0)));
      float t2 = fmaf(Mr[11], A3, fmaf(Mr[10], A2, fmaf(Mr[9], A1, Mr[8] * A0)));
      float t3 = fmaf(Mr[15], A3, fmaf(Mr[14], A2, fmaf(Mr[13], A1, Mr[12] * A0)));
      float tdot = fmaf(t3, B3, fmaf(t2, B2, fmaf(t1, B1, t0 * B0)));

      // sv[mz] via per-bit selects
      float svm = ((mz & 1) ? sq[0] : cq[0]);
      svm *= ((mz & 2) ? sq[1] : cq[1]);
      svm *= ((mz & 4) ? sq[2] : cq[2]);
      svm *= ((mz & 8) ? sq[3] : cq[3]);

      float p = tdot * svm;
#pragma unroll
      for (int off = 8; off; off >>= 1) p += __shfl_xor(p, off);
      // p = qf_g; exchange across 16-lane groups
      float v1 = __shfl_xor(p, 16);   // qf_{g^1}
      float v2 = __shfl_xor(p, 32);   // qf_{g^2}
      float v3 = __shfl_xor(v1, 32);  // qf_{g^3}

      float mu = fmaf(v3, wmuP[3], fmaf(v2, wmuP[2], fmaf(v1, wmuP[1], fmaf(p, wmuP[0], bmur))));
      float lv = fmaf(v3, wlvP[3], fmaf(v2, wlvP[2], fmaf(v1, wlvP[1], fmaf(p, wlvP[0], blvr))));
      __builtin_nontemporal_store(mu, out + (size_t)r * 64 + lane);
      __builtin_nontemporal_store(lv, out + lv_base + (size_t)r * 64 + lane);

      if (rn >= B) break;
      r = rn;
    }
  }
}

extern "C" void kernel_launch(void* const* d_in, const int* in_sizes, int n_in,
                              void* d_out, int out_size, void* d_ws, size_t ws_size,
                              hipStream_t stream) {
  const float* x   = (const float*)d_in[0];
  const float* W1  = (const float*)d_in[1];
  const float* b1  = (const float*)d_in[2];
  const float* qp  = (const float*)d_in[3];
  const float* Wmu = (const float*)d_in[4];
  const float* bmu = (const float*)d_in[5];
  const float* Wlv = (const float*)d_in[6];
  const float* blv = (const float*)d_in[7];
  float* out = (float*)d_out;

  const int B = out_size / 128;  // out = mu(B,64) ++ logvar(B,64)

  int blocks = (B + 31) / 32;    // 4 waves/block, 8 rows/wave at B=32768
  if (blocks > 1024) blocks = 1024;
  fused_qenc_kernel<<<blocks, 256, 0, stream>>>(x, W1, b1, qp, Wmu, bmu, Wlv, blv,
                                                out, B);
}